// Round 5
// baseline (564.036 us; speedup 1.0000x reference)
//
#include <hip/hip_runtime.h>

#define NNODES 100000
#define NEDGES 625000
#define DIM 128
#define TM 32            // nodes per block (100000 = 3125*32 exact)
#define LDSPAD 132
#define SCAN_B 1024
#define NSCAN ((NNODES + SCAN_B - 1) / SCAN_B)   // 98
#define SRCMASK 0x07FFFFFF

typedef unsigned short ushort8 __attribute__((ext_vector_type(8)));

// --- transpose W_l, W_r into WT[m][k][c] = W_m[c][k] ---
__global__ void transpose_w_kernel(const float* __restrict__ Wl,
                                   const float* __restrict__ Wr,
                                   float* __restrict__ WT) {
    int tid = blockIdx.x * blockDim.x + threadIdx.x;
    if (tid >= 2 * DIM * DIM) return;
    int m   = tid >> 14;
    int idx = tid & (DIM * DIM - 1);
    int k   = idx >> 7;
    int c   = idx & (DIM - 1);
    const float* W = m ? Wr : Wl;
    WT[tid] = W[c * DIM + k];
}

// --- x (fp32) -> xh (bf16 bits, RNE) ---
__global__ void convert_kernel(const float* __restrict__ x,
                               unsigned short* __restrict__ xh) {
    int i = (blockIdx.x * 256 + threadIdx.x) * 8;
    if (i >= NNODES * DIM) return;
    float4 a = *(const float4*)(x + i);
    float4 b = *(const float4*)(x + i + 4);
    ushort8 o;
    const float* f[8] = {&a.x, &a.y, &a.z, &a.w, &b.x, &b.y, &b.z, &b.w};
#pragma unroll
    for (int k = 0; k < 8; ++k) {
        unsigned u = __float_as_uint(*f[k]);
        u += 0x7FFF + ((u >> 16) & 1);
        o[k] = (unsigned short)(u >> 16);
    }
    *(ushort8*)(xh + i) = o;
}

// --- CSR 1: degree histogram over destinations ---
__global__ void degree_kernel(const int* __restrict__ ei, int* __restrict__ deg) {
    int e = blockIdx.x * blockDim.x + threadIdx.x;
    if (e < NEDGES) atomicAdd(&deg[ei[NEDGES + e]], 1);
}

// --- CSR 2a: per-block sums ---
__global__ __launch_bounds__(1024) void block_sum_kernel(const int* __restrict__ deg,
                                                         int* __restrict__ bsum) {
    __shared__ int red[SCAN_B];
    int gid = blockIdx.x * SCAN_B + threadIdx.x;
    red[threadIdx.x] = (gid < NNODES) ? deg[gid] : 0;
    __syncthreads();
    for (int s = SCAN_B / 2; s > 0; s >>= 1) {
        if (threadIdx.x < s) red[threadIdx.x] += red[threadIdx.x + s];
        __syncthreads();
    }
    if (threadIdx.x == 0) bsum[blockIdx.x] = red[0];
}

// --- CSR 2b: scan the 98 block sums ---
__global__ void scan_small_kernel(const int* __restrict__ bsum, int* __restrict__ boff) {
    __shared__ int v[128];
    int t = threadIdx.x;
    int orig = (t < NSCAN) ? bsum[t] : 0;
    v[t] = orig;
    __syncthreads();
    for (int d = 1; d < 128; d <<= 1) {
        int add = (t >= d) ? v[t - d] : 0;
        __syncthreads();
        v[t] += add;
        __syncthreads();
    }
    if (t < NSCAN) boff[t] = v[t] - orig;
}

// --- CSR 2c: per-block exclusive scan + block offset ---
__global__ __launch_bounds__(1024) void scan_block_kernel(const int* __restrict__ deg,
                                                          const int* __restrict__ boff,
                                                          int* __restrict__ off) {
    __shared__ int v[SCAN_B];
    int t = threadIdx.x;
    int gid = blockIdx.x * SCAN_B + t;
    int orig = (gid < NNODES) ? deg[gid] : 0;
    v[t] = orig;
    __syncthreads();
    for (int d = 1; d < SCAN_B; d <<= 1) {
        int add = (t >= d) ? v[t - d] : 0;
        __syncthreads();
        v[t] += add;
        __syncthreads();
    }
    if (gid < NNODES) off[gid] = boff[blockIdx.x] + v[t] - orig;
    if (gid == 0) off[NNODES] = NEDGES;
}

// --- CSR 3: fill adjacency, packing dst-local index in bits 27..31 ---
__global__ void fill_kernel(const int* __restrict__ ei, const int* __restrict__ off,
                            int* __restrict__ cursor, int* __restrict__ adj) {
    int e = blockIdx.x * blockDim.x + threadIdx.x;
    if (e >= NEDGES) return;
    int src = ei[e];
    int dst = ei[NEDGES + e];
    int old = atomicSub(&cursor[dst], 1);
    adj[off[dst] + old - 1] = src | ((dst & (TM - 1)) << 27);
}

// ============ Phase B (shared by both fused variants) ============
__device__ __forceinline__ void phase_b(const float* __restrict__ x,
                                        const float* __restrict__ WT,
                                        const float* __restrict__ bias,
                                        float* __restrict__ out,
                                        const float (*mean)[LDSPAD], int base,
                                        int tid) {
    const int colgrp = tid & 15;
    const int rowgrp = tid >> 4;
    const int c0  = colgrp * 8;
    const int lr0 = rowgrp * 2;
    const int r0  = base + lr0;

    const float* WTl = WT;
    const float* WTr = WT + DIM * DIM;

    float acc[2][8];
#pragma unroll
    for (int i = 0; i < 2; ++i)
#pragma unroll
        for (int j = 0; j < 8; ++j) acc[i][j] = 0.0f;

    for (int k4 = 0; k4 < DIM / 4; ++k4) {
        float4 am[2], axv[2];
#pragma unroll
        for (int i = 0; i < 2; ++i) {
            am[i]  = *(const float4*)(&mean[lr0 + i][k4 * 4]);
            axv[i] = *(const float4*)(x + (size_t)(r0 + i) * DIM + k4 * 4);
        }
#pragma unroll
        for (int kk = 0; kk < 4; ++kk) {
            int k = k4 * 4 + kk;
            float4 wl0 = *(const float4*)(WTl + k * DIM + c0);
            float4 wl1 = *(const float4*)(WTl + k * DIM + c0 + 4);
            float4 wr0 = *(const float4*)(WTr + k * DIM + c0);
            float4 wr1 = *(const float4*)(WTr + k * DIM + c0 + 4);
#pragma unroll
            for (int i = 0; i < 2; ++i) {
                float m  = (&am[i].x)[kk];
                float xv = (&axv[i].x)[kk];
                acc[i][0] += m * wl0.x + xv * wr0.x;
                acc[i][1] += m * wl0.y + xv * wr0.y;
                acc[i][2] += m * wl0.z + xv * wr0.z;
                acc[i][3] += m * wl0.w + xv * wr0.w;
                acc[i][4] += m * wl1.x + xv * wr1.x;
                acc[i][5] += m * wl1.y + xv * wr1.y;
                acc[i][6] += m * wl1.z + xv * wr1.z;
                acc[i][7] += m * wl1.w + xv * wr1.w;
            }
        }
    }

    float4 b0 = *(const float4*)(bias + c0);
    float4 b1 = *(const float4*)(bias + c0 + 4);
#pragma unroll
    for (int i = 0; i < 2; ++i) {
        float4 o0v, o1v;
        o0v.x = fmaxf(acc[i][0] + b0.x, 0.0f);
        o0v.y = fmaxf(acc[i][1] + b0.y, 0.0f);
        o0v.z = fmaxf(acc[i][2] + b0.z, 0.0f);
        o0v.w = fmaxf(acc[i][3] + b0.w, 0.0f);
        o1v.x = fmaxf(acc[i][4] + b1.x, 0.0f);
        o1v.y = fmaxf(acc[i][5] + b1.y, 0.0f);
        o1v.z = fmaxf(acc[i][6] + b1.z, 0.0f);
        o1v.w = fmaxf(acc[i][7] + b1.w, 0.0f);
        *(float4*)(out + (size_t)(r0 + i) * DIM + c0)     = o0v;
        *(float4*)(out + (size_t)(r0 + i) * DIM + c0 + 4) = o1v;
    }
}

// ============ fused, bf16 gather path ============
// Phase A: edge-parallel. 16 slots x 16 lanes; each slot streams the block's
// edge list with stride 16, 2-deep pipelined -> 32 rows in flight per block.
// Accumulate pre-scaled (1/deg) values into LDS via ds_add_f32.
__global__ __launch_bounds__(256) void fused_bf16_kernel(
    const float* __restrict__ x,
    const unsigned short* __restrict__ xh,
    const int*   __restrict__ off,
    const int*   __restrict__ adj,
    const float* __restrict__ WT,
    const float* __restrict__ bias,
    float* __restrict__ out)
{
    __shared__ float mean[TM][LDSPAD];
    __shared__ float invd[TM];
    const int tid  = threadIdx.x;
    const int base = blockIdx.x * TM;

    {   // zero accum + per-node 1/deg
        int r = tid >> 3, cb = (tid & 7) * 16;
        float4 z; z.x = z.y = z.z = z.w = 0.0f;
        *(float4*)&mean[r][cb]      = z;
        *(float4*)&mean[r][cb + 4]  = z;
        *(float4*)&mean[r][cb + 8]  = z;
        *(float4*)&mean[r][cb + 12] = z;
        if (tid < TM) {
            int d = off[base + tid + 1] - off[base + tid];
            invd[tid] = 1.0f / fmaxf((float)d, 1.0f);
        }
    }
    __syncthreads();

    const int slot = tid >> 4;      // 0..15
    const int ql   = tid & 15;      // 16 lanes x 8 bf16 = 128 cols
    const int estart = off[base], eend = off[base + TM];

    int e = estart + slot;
    for (; e + 16 < eend; e += 32) {
        int p0 = adj[e];
        int p1 = adj[e + 16];
        int s0 = p0 & SRCMASK; int l0 = ((unsigned)p0) >> 27;
        int s1 = p1 & SRCMASK; int l1 = ((unsigned)p1) >> 27;
        ushort8 r0 = *(const ushort8*)(xh + (size_t)s0 * DIM + ql * 8);
        ushort8 r1 = *(const ushort8*)(xh + (size_t)s1 * DIM + ql * 8);
        float i0 = invd[l0], i1 = invd[l1];
#pragma unroll
        for (int k = 0; k < 8; ++k) {
            float f = __uint_as_float(((unsigned)r0[k]) << 16);
            atomicAdd(&mean[l0][ql * 8 + k], f * i0);
        }
#pragma unroll
        for (int k = 0; k < 8; ++k) {
            float f = __uint_as_float(((unsigned)r1[k]) << 16);
            atomicAdd(&mean[l1][ql * 8 + k], f * i1);
        }
    }
    if (e < eend) {
        int p0 = adj[e];
        int s0 = p0 & SRCMASK; int l0 = ((unsigned)p0) >> 27;
        ushort8 r0 = *(const ushort8*)(xh + (size_t)s0 * DIM + ql * 8);
        float i0 = invd[l0];
#pragma unroll
        for (int k = 0; k < 8; ++k) {
            float f = __uint_as_float(((unsigned)r0[k]) << 16);
            atomicAdd(&mean[l0][ql * 8 + k], f * i0);
        }
    }
    __syncthreads();

    phase_b(x, WT, bias, out, mean, base, tid);
}

// ============ fused, fp32 gather fallback (small ws) ============
__global__ __launch_bounds__(256) void fused_f32_kernel(
    const float* __restrict__ x,
    const int*   __restrict__ off,
    const int*   __restrict__ adj,
    const float* __restrict__ WT,
    const float* __restrict__ bias,
    float* __restrict__ out)
{
    __shared__ float mean[TM][LDSPAD];
    __shared__ float invd[TM];
    const int tid  = threadIdx.x;
    const int base = blockIdx.x * TM;

    {
        int r = tid >> 3, cb = (tid & 7) * 16;
        float4 z; z.x = z.y = z.z = z.w = 0.0f;
        *(float4*)&mean[r][cb]      = z;
        *(float4*)&mean[r][cb + 4]  = z;
        *(float4*)&mean[r][cb + 8]  = z;
        *(float4*)&mean[r][cb + 12] = z;
        if (tid < TM) {
            int d = off[base + tid + 1] - off[base + tid];
            invd[tid] = 1.0f / fmaxf((float)d, 1.0f);
        }
    }
    __syncthreads();

    const int slot = tid >> 5;      // 0..7
    const int l32  = tid & 31;      // 32 lanes x float4 = 128 cols
    const int estart = off[base], eend = off[base + TM];

    int e = estart + slot;
    for (; e + 8 < eend; e += 16) {
        int p0 = adj[e];
        int p1 = adj[e + 8];
        int s0 = p0 & SRCMASK; int l0 = ((unsigned)p0) >> 27;
        int s1 = p1 & SRCMASK; int l1 = ((unsigned)p1) >> 27;
        float4 v0 = *(const float4*)(x + (size_t)s0 * DIM + 4 * l32);
        float4 v1 = *(const float4*)(x + (size_t)s1 * DIM + 4 * l32);
        float i0 = invd[l0], i1 = invd[l1];
        atomicAdd(&mean[l0][4 * l32],     v0.x * i0);
        atomicAdd(&mean[l0][4 * l32 + 1], v0.y * i0);
        atomicAdd(&mean[l0][4 * l32 + 2], v0.z * i0);
        atomicAdd(&mean[l0][4 * l32 + 3], v0.w * i0);
        atomicAdd(&mean[l1][4 * l32],     v1.x * i1);
        atomicAdd(&mean[l1][4 * l32 + 1], v1.y * i1);
        atomicAdd(&mean[l1][4 * l32 + 2], v1.z * i1);
        atomicAdd(&mean[l1][4 * l32 + 3], v1.w * i1);
    }
    if (e < eend) {
        int p0 = adj[e];
        int s0 = p0 & SRCMASK; int l0 = ((unsigned)p0) >> 27;
        float4 v0 = *(const float4*)(x + (size_t)s0 * DIM + 4 * l32);
        float i0 = invd[l0];
        atomicAdd(&mean[l0][4 * l32],     v0.x * i0);
        atomicAdd(&mean[l0][4 * l32 + 1], v0.y * i0);
        atomicAdd(&mean[l0][4 * l32 + 2], v0.z * i0);
        atomicAdd(&mean[l0][4 * l32 + 3], v0.w * i0);
    }
    __syncthreads();

    phase_b(x, WT, bias, out, mean, base, tid);
}

extern "C" void kernel_launch(void* const* d_in, const int* in_sizes, int n_in,
                              void* d_out, int out_size, void* d_ws, size_t ws_size,
                              hipStream_t stream) {
    const float* x  = (const float*)d_in[0];
    const int*   ei = (const int*)d_in[1];   // int32 (harness converts int64)
    const float* Wl = (const float*)d_in[2];
    const float* Wr = (const float*)d_in[3];
    const float* b  = (const float*)d_in[4];
    float* out = (float*)d_out;

    // ws layout:
    //   [0,     512K) off   int[NNODES+1]
    //   [512K, 1024K) deg   int[NNODES] (doubles as fill cursor)
    //   [1M,    3.5M) adj   int[NEDGES] (packed: src | dst_local<<27)
    //   [3.5M,  +4K ) bsum ; [3.5M+4K, +4K) boff
    //   [4M,  4.125M) WT    float[2*DIM*DIM]
    //   [4.5M, +25.6M) xh   bf16[NNODES*DIM]   (only if ws is big enough)
    int*   off  = (int*)d_ws;
    int*   deg  = (int*)((char*)d_ws + (512 << 10));
    int*   adj  = (int*)((char*)d_ws + (1 << 20));
    int*   bsum = (int*)((char*)d_ws + 3584 * 1024);
    int*   boff = (int*)((char*)d_ws + 3588 * 1024);
    float* WT   = (float*)((char*)d_ws + (4 << 20));
    unsigned short* xh = (unsigned short*)((char*)d_ws + 4608 * 1024);

    const size_t need_bf16 = 4608 * 1024 + (size_t)NNODES * DIM * 2;
    const bool use_bf16 = (ws_size >= need_bf16);

    hipMemsetAsync(deg, 0, NNODES * sizeof(int), stream);

    transpose_w_kernel<<<(2 * DIM * DIM + 255) / 256, 256, 0, stream>>>(Wl, Wr, WT);
    degree_kernel<<<(NEDGES + 255) / 256, 256, 0, stream>>>(ei, deg);
    block_sum_kernel<<<NSCAN, SCAN_B, 0, stream>>>(deg, bsum);
    scan_small_kernel<<<1, 128, 0, stream>>>(bsum, boff);
    scan_block_kernel<<<NSCAN, SCAN_B, 0, stream>>>(deg, boff, off);
    fill_kernel<<<(NEDGES + 255) / 256, 256, 0, stream>>>(ei, off, deg, adj);

    if (use_bf16) {
        convert_kernel<<<NNODES * DIM / 8 / 256, 256, 0, stream>>>(x, xh);
        fused_bf16_kernel<<<NNODES / TM, 256, 0, stream>>>(x, xh, off, adj, WT, b, out);
    } else {
        fused_f32_kernel<<<NNODES / TM, 256, 0, stream>>>(x, off, adj, WT, b, out);
    }
}

// Round 6
// 196.194 us; speedup vs baseline: 2.8749x; 2.8749x over previous
//
#include <hip/hip_runtime.h>

#define NNODES 100000
#define NEDGES 625000
#define DIM 128
#define SCAN_B 1024
#define NSCAN ((NNODES + SCAN_B - 1) / SCAN_B)   // 98

typedef short short8 __attribute__((ext_vector_type(8)));
typedef float f32x4  __attribute__((ext_vector_type(4)));

__device__ __forceinline__ unsigned short f2bf(float f) {
    unsigned u = __float_as_uint(f);
    u += 0x7FFFu + ((u >> 16) & 1u);          // RNE
    return (unsigned short)(u >> 16);
}

// --- W (fp32 [c][k]) -> Wh (bf16 [256][128], Wl rows then Wr rows) ---
__global__ void convert_w_kernel(const float* __restrict__ Wl,
                                 const float* __restrict__ Wr,
                                 unsigned short* __restrict__ Wh) {
    int i = blockIdx.x * 256 + threadIdx.x;
    if (i >= 2 * DIM * DIM) return;
    const float* W = (i < DIM * DIM) ? Wl : Wr;
    Wh[i] = f2bf(W[i & (DIM * DIM - 1)]);
}

// --- CSR 1: degree histogram over destinations ---
__global__ void degree_kernel(const int* __restrict__ ei, int* __restrict__ deg) {
    int e = blockIdx.x * blockDim.x + threadIdx.x;
    if (e < NEDGES) atomicAdd(&deg[ei[NEDGES + e]], 1);
}

// --- CSR 2a: per-block sums ---
__global__ __launch_bounds__(1024) void block_sum_kernel(const int* __restrict__ deg,
                                                         int* __restrict__ bsum) {
    __shared__ int red[SCAN_B];
    int gid = blockIdx.x * SCAN_B + threadIdx.x;
    red[threadIdx.x] = (gid < NNODES) ? deg[gid] : 0;
    __syncthreads();
    for (int s = SCAN_B / 2; s > 0; s >>= 1) {
        if (threadIdx.x < s) red[threadIdx.x] += red[threadIdx.x + s];
        __syncthreads();
    }
    if (threadIdx.x == 0) bsum[blockIdx.x] = red[0];
}

// --- CSR 2b: scan the 98 block sums ---
__global__ void scan_small_kernel(const int* __restrict__ bsum, int* __restrict__ boff) {
    __shared__ int v[128];
    int t = threadIdx.x;
    int orig = (t < NSCAN) ? bsum[t] : 0;
    v[t] = orig;
    __syncthreads();
    for (int d = 1; d < 128; d <<= 1) {
        int add = (t >= d) ? v[t - d] : 0;
        __syncthreads();
        v[t] += add;
        __syncthreads();
    }
    if (t < NSCAN) boff[t] = v[t] - orig;
}

// --- CSR 2c: per-block exclusive scan + block offset ---
__global__ __launch_bounds__(1024) void scan_block_kernel(const int* __restrict__ deg,
                                                          const int* __restrict__ boff,
                                                          int* __restrict__ off) {
    __shared__ int v[SCAN_B];
    int t = threadIdx.x;
    int gid = blockIdx.x * SCAN_B + t;
    int orig = (gid < NNODES) ? deg[gid] : 0;
    v[t] = orig;
    __syncthreads();
    for (int d = 1; d < SCAN_B; d <<= 1) {
        int add = (t >= d) ? v[t - d] : 0;
        __syncthreads();
        v[t] += add;
        __syncthreads();
    }
    if (gid < NNODES) off[gid] = boff[blockIdx.x] + v[t] - orig;
    if (gid == 0) off[NNODES] = NEDGES;
}

// --- CSR 3: fill adjacency (plain src); reuses deg as countdown cursor ---
__global__ void fill_kernel(const int* __restrict__ ei, const int* __restrict__ off,
                            int* __restrict__ cursor, int* __restrict__ adj) {
    int e = blockIdx.x * blockDim.x + threadIdx.x;
    if (e >= NEDGES) return;
    int src = ei[e];
    int dst = ei[NEDGES + e];
    int old = atomicSub(&cursor[dst], 1);
    adj[off[dst] + old - 1] = src;
}

// --- dense GEMM: [Y|Z] = x @ [Wl|Wr]^T via mfma_f32_16x16x32_bf16 ---
// block = 256 = 4 waves; block tile 64 rows; each wave 16 rows x 256 cols.
// A-frag: lane holds x[row0+(l&15)][ks*32+(l>>4)*8 ..+7] (fp32->bf16 in-reg).
// B-frag: lane holds W[ct*16+(l&15)][ks*32+(l>>4)*8 ..+7] (original layout!).
// D: row = row0+(l>>4)*4+reg, col = ct*16+(l&15)  [m89-verified mapping].
__global__ __launch_bounds__(256) void gemm_kernel(
    const float* __restrict__ x,
    const unsigned short* __restrict__ Wh,   // [256][128] bf16
    unsigned short* __restrict__ Yh,         // [NNODES][128] bf16
    float* __restrict__ Z)                   // = d_out
{
    const int wave = threadIdx.x >> 6;
    const int lane = threadIdx.x & 63;
    const int row0 = blockIdx.x * 64 + wave * 16;
    if (row0 >= NNODES) return;

    const int lrow = lane & 15;
    const int kgrp = lane >> 4;

    int arow = row0 + lrow;
    if (arow >= NNODES) arow = NNODES - 1;    // clamped rows never stored
    const float* xrow = x + (size_t)arow * DIM + kgrp * 8;
    const unsigned short* wbase = Wh + (size_t)lrow * DIM + kgrp * 8;

    f32x4 acc[16];
#pragma unroll
    for (int i = 0; i < 16; ++i) acc[i] = (f32x4){0.f, 0.f, 0.f, 0.f};

#pragma unroll
    for (int ks = 0; ks < 4; ++ks) {
        float4 a0 = *(const float4*)(xrow + ks * 32);
        float4 a1 = *(const float4*)(xrow + ks * 32 + 4);
        short8 af;
        af[0] = (short)f2bf(a0.x); af[1] = (short)f2bf(a0.y);
        af[2] = (short)f2bf(a0.z); af[3] = (short)f2bf(a0.w);
        af[4] = (short)f2bf(a1.x); af[5] = (short)f2bf(a1.y);
        af[6] = (short)f2bf(a1.z); af[7] = (short)f2bf(a1.w);
#pragma unroll
        for (int ct = 0; ct < 16; ++ct) {
            short8 bf = *(const short8*)(wbase + (size_t)ct * 16 * DIM + ks * 32);
            acc[ct] = __builtin_amdgcn_mfma_f32_16x16x32_bf16(af, bf, acc[ct], 0, 0, 0);
        }
    }

#pragma unroll
    for (int ct = 0; ct < 16; ++ct) {
        const int col = ct * 16 + lrow;
#pragma unroll
        for (int r = 0; r < 4; ++r) {
            const int row = row0 + kgrp * 4 + r;
            if (row < NNODES) {
                float v = acc[ct][r];
                if (ct < 8) Yh[(size_t)row * DIM + col] = f2bf(v);
                else        Z [(size_t)row * DIM + (col - 128)] = v;
            }
        }
    }
}

// --- aggregate: out[n] = relu(invd * sum_{j in N(n)} Y[j] + Z[n] + b) ---
// one wave per node; lane owns cols {2*lane, 2*lane+1}; 4 rows in flight.
__global__ __launch_bounds__(256) void aggregate_kernel(
    const unsigned short* __restrict__ Yh,
    const int* __restrict__ off,
    const int* __restrict__ adj,
    const float* __restrict__ bias,
    float* __restrict__ out)                 // in: Z, out: result (in-place)
{
    const int wave = threadIdx.x >> 6;
    const int lane = threadIdx.x & 63;
    const int n = blockIdx.x * 4 + wave;
    if (n >= NNODES) return;

    const int o0 = off[n], o1 = off[n + 1];
    float ax = 0.f, ay = 0.f;

    int j = o0;
    for (; j + 4 <= o1; j += 4) {
        int s0 = adj[j], s1 = adj[j + 1], s2 = adj[j + 2], s3 = adj[j + 3];
        unsigned v0 = *(const unsigned*)(Yh + (size_t)s0 * DIM + lane * 2);
        unsigned v1 = *(const unsigned*)(Yh + (size_t)s1 * DIM + lane * 2);
        unsigned v2 = *(const unsigned*)(Yh + (size_t)s2 * DIM + lane * 2);
        unsigned v3 = *(const unsigned*)(Yh + (size_t)s3 * DIM + lane * 2);
        ax += __uint_as_float(v0 << 16) + __uint_as_float(v1 << 16)
            + __uint_as_float(v2 << 16) + __uint_as_float(v3 << 16);
        ay += __uint_as_float(v0 & 0xFFFF0000u) + __uint_as_float(v1 & 0xFFFF0000u)
            + __uint_as_float(v2 & 0xFFFF0000u) + __uint_as_float(v3 & 0xFFFF0000u);
    }
    for (; j < o1; ++j) {
        unsigned v = *(const unsigned*)(Yh + (size_t)adj[j] * DIM + lane * 2);
        ax += __uint_as_float(v << 16);
        ay += __uint_as_float(v & 0xFFFF0000u);
    }

    const float invd = 1.0f / fmaxf((float)(o1 - o0), 1.0f);
    float2 z  = *(const float2*)(out  + (size_t)n * DIM + lane * 2);
    float2 bb = *(const float2*)(bias + lane * 2);
    float2 o;
    o.x = fmaxf(ax * invd + z.x + bb.x, 0.f);
    o.y = fmaxf(ay * invd + z.y + bb.y, 0.f);
    *(float2*)(out + (size_t)n * DIM + lane * 2) = o;
}

extern "C" void kernel_launch(void* const* d_in, const int* in_sizes, int n_in,
                              void* d_out, int out_size, void* d_ws, size_t ws_size,
                              hipStream_t stream) {
    const float* x  = (const float*)d_in[0];
    const int*   ei = (const int*)d_in[1];   // int32 (harness converts int64)
    const float* Wl = (const float*)d_in[2];
    const float* Wr = (const float*)d_in[3];
    const float* b  = (const float*)d_in[4];
    float* out = (float*)d_out;

    // ws layout (~29.6 MB; round-5 proved ws >= 30.1 MB):
    //   [0,     512K) off   int[NNODES+1]
    //   [512K,    1M) deg   int[NNODES] (doubles as fill cursor)
    //   [1M,    3.5M) adj   int[NEDGES]
    //   [3.5M,  +4K ) bsum ; [3.5M+4K, +4K) boff
    //   [3.75M, +64K) Wh    bf16[256*128]
    //   [4M,  +25.6M) Yh    bf16[NNODES*128]
    int*            off  = (int*)d_ws;
    int*            deg  = (int*)((char*)d_ws + (512 << 10));
    int*            adj  = (int*)((char*)d_ws + (1 << 20));
    int*            bsum = (int*)((char*)d_ws + 3584 * 1024);
    int*            boff = (int*)((char*)d_ws + 3588 * 1024);
    unsigned short* Wh   = (unsigned short*)((char*)d_ws + 3840 * 1024);
    unsigned short* Yh   = (unsigned short*)((char*)d_ws + (4 << 20));

    hipMemsetAsync(deg, 0, NNODES * sizeof(int), stream);

    convert_w_kernel<<<(2 * DIM * DIM + 255) / 256, 256, 0, stream>>>(Wl, Wr, Wh);
    degree_kernel<<<(NEDGES + 255) / 256, 256, 0, stream>>>(ei, deg);
    block_sum_kernel<<<NSCAN, SCAN_B, 0, stream>>>(deg, bsum);
    scan_small_kernel<<<1, 128, 0, stream>>>(bsum, boff);
    scan_block_kernel<<<NSCAN, SCAN_B, 0, stream>>>(deg, boff, off);
    fill_kernel<<<(NEDGES + 255) / 256, 256, 0, stream>>>(ei, off, deg, adj);

    gemm_kernel<<<(NNODES + 63) / 64, 256, 0, stream>>>(x, Wh, Yh, out);
    aggregate_kernel<<<(NNODES + 3) / 4, 256, 0, stream>>>(Yh, off, adj, b, out);
}

// Round 8
// 189.086 us; speedup vs baseline: 2.9830x; 1.0376x over previous
//
#include <hip/hip_runtime.h>

#define NNODES 100000
#define NEDGES 625000
#define DIM 128
#define SCAN_B 1024
#define NSCAN ((NNODES + SCAN_B - 1) / SCAN_B)   // 98
#define YSTRIDE 136     // padded LDS row stride in shorts (272B, 16B-aligned)

typedef short short8 __attribute__((ext_vector_type(8)));
typedef unsigned short ushort8 __attribute__((ext_vector_type(8)));
typedef float f32x4  __attribute__((ext_vector_type(4)));

__device__ __forceinline__ unsigned short f2bf(float f) {
    unsigned u = __float_as_uint(f);
    u += 0x7FFFu + ((u >> 16) & 1u);          // RNE
    return (unsigned short)(u >> 16);
}

// --- W (fp32 [c][k]) -> Wh (bf16 [256][128], Wl rows then Wr rows) ---
__global__ void convert_w_kernel(const float* __restrict__ Wl,
                                 const float* __restrict__ Wr,
                                 unsigned short* __restrict__ Wh) {
    int i = blockIdx.x * 256 + threadIdx.x;
    if (i >= 2 * DIM * DIM) return;
    const float* W = (i < DIM * DIM) ? Wl : Wr;
    Wh[i] = f2bf(W[i & (DIM * DIM - 1)]);
}

// --- CSR 1: degree histogram over destinations ---
__global__ void degree_kernel(const int* __restrict__ ei, int* __restrict__ deg) {
    int e = blockIdx.x * blockDim.x + threadIdx.x;
    if (e < NEDGES) atomicAdd(&deg[ei[NEDGES + e]], 1);
}

// --- CSR 2a: per-block sums ---
__global__ __launch_bounds__(1024) void block_sum_kernel(const int* __restrict__ deg,
                                                         int* __restrict__ bsum) {
    __shared__ int red[SCAN_B];
    int gid = blockIdx.x * SCAN_B + threadIdx.x;
    red[threadIdx.x] = (gid < NNODES) ? deg[gid] : 0;
    __syncthreads();
    for (int s = SCAN_B / 2; s > 0; s >>= 1) {
        if (threadIdx.x < s) red[threadIdx.x] += red[threadIdx.x + s];
        __syncthreads();
    }
    if (threadIdx.x == 0) bsum[blockIdx.x] = red[0];
}

// --- CSR 2b: scan the 98 block sums ---
__global__ void scan_small_kernel(const int* __restrict__ bsum, int* __restrict__ boff) {
    __shared__ int v[128];
    int t = threadIdx.x;
    int orig = (t < NSCAN) ? bsum[t] : 0;
    v[t] = orig;
    __syncthreads();
    for (int d = 1; d < 128; d <<= 1) {
        int add = (t >= d) ? v[t - d] : 0;
        __syncthreads();
        v[t] += add;
        __syncthreads();
    }
    if (t < NSCAN) boff[t] = v[t] - orig;
}

// --- CSR 2c: per-block exclusive scan + block offset ---
__global__ __launch_bounds__(1024) void scan_block_kernel(const int* __restrict__ deg,
                                                          const int* __restrict__ boff,
                                                          int* __restrict__ off) {
    __shared__ int v[SCAN_B];
    int t = threadIdx.x;
    int gid = blockIdx.x * SCAN_B + t;
    int orig = (gid < NNODES) ? deg[gid] : 0;
    v[t] = orig;
    __syncthreads();
    for (int d = 1; d < SCAN_B; d <<= 1) {
        int add = (t >= d) ? v[t - d] : 0;
        __syncthreads();
        v[t] += add;
        __syncthreads();
    }
    if (gid < NNODES) off[gid] = boff[blockIdx.x] + v[t] - orig;
    if (gid == 0) off[NNODES] = NEDGES;
}

// --- CSR 3: fill adjacency; reuses deg as countdown cursor ---
__global__ void fill_kernel(const int* __restrict__ ei, const int* __restrict__ off,
                            int* __restrict__ cursor, int* __restrict__ adj) {
    int e = blockIdx.x * blockDim.x + threadIdx.x;
    if (e >= NEDGES) return;
    int src = ei[e];
    int dst = ei[NEDGES + e];
    int old = atomicSub(&cursor[dst], 1);
    adj[off[dst] + old - 1] = src;
}

// --- dense GEMM: [Y|Z] = x @ [Wl|Wr]^T via mfma_f32_16x16x32_bf16 ---
// block = 256 = 4 waves; wave = 16 rows x 256 cols.
// Y epilogue staged via LDS; cross-lane LDS exchange REQUIRES the barrier
// (round-7 post-timing divergence traced to barrierless write->read).
// Inactive waves (last block) stay alive for the barrier: no early return.
__global__ __launch_bounds__(256) void gemm_kernel(
    const float* __restrict__ x,
    const unsigned short* __restrict__ Wh,   // [256][128] bf16
    unsigned short* __restrict__ Yh,         // [NNODES][128] bf16
    float* __restrict__ Z)                   // = d_out
{
    __shared__ unsigned short ylds[4][16 * YSTRIDE];
    const int wave = threadIdx.x >> 6;
    const int lane = threadIdx.x & 63;
    const int row0 = blockIdx.x * 64 + wave * 16;
    const bool active = (row0 < NNODES);     // whole-wave uniform

    const int lrow = lane & 15;
    const int kgrp = lane >> 4;

    f32x4 acc[16];
#pragma unroll
    for (int i = 0; i < 16; ++i) acc[i] = (f32x4){0.f, 0.f, 0.f, 0.f};

    if (active) {
        const float* xrow = x + (size_t)(row0 + lrow) * DIM + kgrp * 8;
        const unsigned short* wbase = Wh + (size_t)lrow * DIM + kgrp * 8;
#pragma unroll
        for (int ks = 0; ks < 4; ++ks) {
            float4 a0 = *(const float4*)(xrow + ks * 32);
            float4 a1 = *(const float4*)(xrow + ks * 32 + 4);
            short8 af;
            af[0] = (short)f2bf(a0.x); af[1] = (short)f2bf(a0.y);
            af[2] = (short)f2bf(a0.z); af[3] = (short)f2bf(a0.w);
            af[4] = (short)f2bf(a1.x); af[5] = (short)f2bf(a1.y);
            af[6] = (short)f2bf(a1.z); af[7] = (short)f2bf(a1.w);
#pragma unroll
            for (int ct = 0; ct < 16; ++ct) {
                short8 bf = *(const short8*)(wbase + (size_t)ct * 16 * DIM + ks * 32);
                acc[ct] = __builtin_amdgcn_mfma_f32_16x16x32_bf16(af, bf, acc[ct], 0, 0, 0);
            }
        }

        // Y half -> LDS stage (cross-lane exchange, read after barrier)
        unsigned short* wl = &ylds[wave][0];
#pragma unroll
        for (int ct = 0; ct < 8; ++ct) {
            const int scol = ct * 16 + lrow;
#pragma unroll
            for (int r = 0; r < 4; ++r)
                wl[(kgrp * 4 + r) * YSTRIDE + scol] = f2bf(acc[ct][r]);
        }
        // Z half: direct fp32 stores (16 lanes x 4B = 64B dense per row-grp)
#pragma unroll
        for (int ct = 8; ct < 16; ++ct) {
            const int col = (ct - 8) * 16 + lrow;
#pragma unroll
            for (int r = 0; r < 4; ++r)
                Z[(size_t)(row0 + kgrp * 4 + r) * DIM + col] = acc[ct][r];
        }
    }

    __syncthreads();   // orders LDS stage before cross-lane readback

    if (active) {
        const unsigned short* wl = &ylds[wave][0];
#pragma unroll
        for (int i = 0; i < 4; ++i) {
            const int row = 4 * i + kgrp;
            ushort8 v = *(const ushort8*)(wl + row * YSTRIDE + lrow * 8);
            *(ushort8*)(Yh + (size_t)(row0 + row) * DIM + lrow * 8) = v;
        }
    }
}

// --- aggregate: out[n] = relu(invd * sum_{j in N(n)} Y[j] + Z[n] + b) ---
// one wave per node; lane owns 2 cols. deg<=8 resolves in ONE parallel
// latency round (clamped in-bounds loads + wave-uniform guards).
__global__ __launch_bounds__(256) void aggregate_kernel(
    const unsigned short* __restrict__ Yh,
    const int* __restrict__ off,
    const int* __restrict__ adj,
    const float* __restrict__ bias,
    float* __restrict__ out)                 // in: Z, out: result (in-place)
{
    const int wave = threadIdx.x >> 6;
    const int lane = threadIdx.x & 63;
    const int n = blockIdx.x * 4 + wave;
    if (n >= NNODES) return;

    const int o0 = off[n], o1 = off[n + 1];
    float ax = 0.f, ay = 0.f;

    if (o0 < o1) {
        int j = o0;
        for (; j + 8 <= o1; j += 8) {        // full batches (deg >= 8)
            int s[8];
#pragma unroll
            for (int k = 0; k < 8; ++k) s[k] = adj[j + k];
            unsigned v[8];
#pragma unroll
            for (int k = 0; k < 8; ++k)
                v[k] = *(const unsigned*)(Yh + (size_t)s[k] * DIM + lane * 2);
#pragma unroll
            for (int k = 0; k < 8; ++k) {
                ax += __uint_as_float(v[k] << 16);
                ay += __uint_as_float(v[k] & 0xFFFF0000u);
            }
        }
        const int rem = o1 - j;              // 0..7, wave-uniform
        if (rem) {
            int s[8];
#pragma unroll
            for (int k = 0; k < 8; ++k) {
                int jj = j + k;
                s[k] = adj[(jj < o1) ? jj : (o1 - 1)];   // clamped: in-bounds
            }
            unsigned v[8];
#pragma unroll
            for (int k = 0; k < 8; ++k)
                v[k] = *(const unsigned*)(Yh + (size_t)s[k] * DIM + lane * 2);
#pragma unroll
            for (int k = 0; k < 8; ++k) {
                if (k < rem) {               // wave-uniform guard
                    ax += __uint_as_float(v[k] << 16);
                    ay += __uint_as_float(v[k] & 0xFFFF0000u);
                }
            }
        }
    }

    const float invd = 1.0f / fmaxf((float)(o1 - o0), 1.0f);
    float2 z  = *(const float2*)(out  + (size_t)n * DIM + lane * 2);
    float2 bb = *(const float2*)(bias + lane * 2);
    float2 o;
    o.x = fmaxf(ax * invd + z.x + bb.x, 0.f);
    o.y = fmaxf(ay * invd + z.y + bb.y, 0.f);
    *(float2*)(out + (size_t)n * DIM + lane * 2) = o;
}

extern "C" void kernel_launch(void* const* d_in, const int* in_sizes, int n_in,
                              void* d_out, int out_size, void* d_ws, size_t ws_size,
                              hipStream_t stream) {
    const float* x  = (const float*)d_in[0];
    const int*   ei = (const int*)d_in[1];   // int32 (harness converts int64)
    const float* Wl = (const float*)d_in[2];
    const float* Wr = (const float*)d_in[3];
    const float* b  = (const float*)d_in[4];
    float* out = (float*)d_out;

    // ws layout (~29.6 MB; round-5 proved ws >= 30.1 MB):
    //   [0,     512K) off   int[NNODES+1]
    //   [512K,    1M) deg   int[NNODES] (doubles as fill cursor)
    //   [1M,    3.5M) adj   int[NEDGES]
    //   [3.5M,  +4K ) bsum ; [3.5M+4K, +4K) boff
    //   [3.75M, +64K) Wh    bf16[256*128]
    //   [4M,  +25.6M) Yh    bf16[NNODES*128]
    int*            off  = (int*)d_ws;
    int*            deg  = (int*)((char*)d_ws + (512 << 10));
    int*            adj  = (int*)((char*)d_ws + (1 << 20));
    int*            bsum = (int*)((char*)d_ws + 3584 * 1024);
    int*            boff = (int*)((char*)d_ws + 3588 * 1024);
    unsigned short* Wh   = (unsigned short*)((char*)d_ws + 3840 * 1024);
    unsigned short* Yh   = (unsigned short*)((char*)d_ws + (4 << 20));

    hipMemsetAsync(deg, 0, NNODES * sizeof(int), stream);

    convert_w_kernel<<<(2 * DIM * DIM + 255) / 256, 256, 0, stream>>>(Wl, Wr, Wh);
    degree_kernel<<<(NEDGES + 255) / 256, 256, 0, stream>>>(ei, deg);
    block_sum_kernel<<<NSCAN, SCAN_B, 0, stream>>>(deg, bsum);
    scan_small_kernel<<<1, 128, 0, stream>>>(bsum, boff);
    scan_block_kernel<<<NSCAN, SCAN_B, 0, stream>>>(deg, boff, off);
    fill_kernel<<<(NEDGES + 255) / 256, 256, 0, stream>>>(ei, off, deg, adj);

    gemm_kernel<<<(NNODES + 63) / 64, 256, 0, stream>>>(x, Wh, Yh, out);
    aggregate_kernel<<<(NNODES + 3) / 4, 256, 0, stream>>>(Yh, off, adj, b, out);
}

// Round 9
// 144.973 us; speedup vs baseline: 3.8906x; 1.3043x over previous
//
#include <hip/hip_runtime.h>

#define NNODES 100000
#define NEDGES 625000
#define DIM 128
#define SCAN_B 1024
#define NSCAN ((NNODES + SCAN_B - 1) / SCAN_B)   // 98
#define YSTRIDE 136     // padded LDS row stride in shorts for Y re-stage

typedef short short8 __attribute__((ext_vector_type(8)));
typedef unsigned short ushort8 __attribute__((ext_vector_type(8)));
typedef float f32x4  __attribute__((ext_vector_type(4)));

__device__ __forceinline__ unsigned short f2bf(float f) {
    unsigned u = __float_as_uint(f);
    u += 0x7FFFu + ((u >> 16) & 1u);          // RNE
    return (unsigned short)(u >> 16);
}

// --- W (fp32 [c][k]) -> Wh (bf16 [256][128], Wl rows then Wr rows) ---
__global__ void convert_w_kernel(const float* __restrict__ Wl,
                                 const float* __restrict__ Wr,
                                 unsigned short* __restrict__ Wh) {
    int i = blockIdx.x * 256 + threadIdx.x;
    if (i >= 2 * DIM * DIM) return;
    const float* W = (i < DIM * DIM) ? Wl : Wr;
    Wh[i] = f2bf(W[i & (DIM * DIM - 1)]);
}

// --- CSR 1: degree histogram over destinations ---
__global__ void degree_kernel(const int* __restrict__ ei, int* __restrict__ deg) {
    int e = blockIdx.x * blockDim.x + threadIdx.x;
    if (e < NEDGES) atomicAdd(&deg[ei[NEDGES + e]], 1);
}

// --- CSR 2a: per-block sums ---
__global__ __launch_bounds__(1024) void block_sum_kernel(const int* __restrict__ deg,
                                                         int* __restrict__ bsum) {
    __shared__ int red[SCAN_B];
    int gid = blockIdx.x * SCAN_B + threadIdx.x;
    red[threadIdx.x] = (gid < NNODES) ? deg[gid] : 0;
    __syncthreads();
    for (int s = SCAN_B / 2; s > 0; s >>= 1) {
        if (threadIdx.x < s) red[threadIdx.x] += red[threadIdx.x + s];
        __syncthreads();
    }
    if (threadIdx.x == 0) bsum[blockIdx.x] = red[0];
}

// --- CSR 2b: scan the 98 block sums ---
__global__ void scan_small_kernel(const int* __restrict__ bsum, int* __restrict__ boff) {
    __shared__ int v[128];
    int t = threadIdx.x;
    int orig = (t < NSCAN) ? bsum[t] : 0;
    v[t] = orig;
    __syncthreads();
    for (int d = 1; d < 128; d <<= 1) {
        int add = (t >= d) ? v[t - d] : 0;
        __syncthreads();
        v[t] += add;
        __syncthreads();
    }
    if (t < NSCAN) boff[t] = v[t] - orig;
}

// --- CSR 2c: per-block exclusive scan + block offset ---
__global__ __launch_bounds__(1024) void scan_block_kernel(const int* __restrict__ deg,
                                                          const int* __restrict__ boff,
                                                          int* __restrict__ off) {
    __shared__ int v[SCAN_B];
    int t = threadIdx.x;
    int gid = blockIdx.x * SCAN_B + t;
    int orig = (gid < NNODES) ? deg[gid] : 0;
    v[t] = orig;
    __syncthreads();
    for (int d = 1; d < SCAN_B; d <<= 1) {
        int add = (t >= d) ? v[t - d] : 0;
        __syncthreads();
        v[t] += add;
        __syncthreads();
    }
    if (gid < NNODES) off[gid] = boff[blockIdx.x] + v[t] - orig;
    if (gid == 0) off[NNODES] = NEDGES;
}

// --- CSR 3: fill adjacency; reuses deg as countdown cursor ---
__global__ void fill_kernel(const int* __restrict__ ei, const int* __restrict__ off,
                            int* __restrict__ cursor, int* __restrict__ adj) {
    int e = blockIdx.x * blockDim.x + threadIdx.x;
    if (e >= NEDGES) return;
    int src = ei[e];
    int dst = ei[NEDGES + e];
    int old = atomicSub(&cursor[dst], 1);
    adj[off[dst] + old - 1] = src;
}

// --- dense GEMM: [Y|Z] = x @ [Wl|Wr]^T via mfma_f32_16x16x32_bf16 ---
// Block = 512 thr = 8 waves x 16 rows = 128 rows. W staged ONCE per block in
// LDS, fragment-major: 16B chunk i=(ct*4+ks)*64+lane holds lane's B-frag for
// (ct,ks) -> B-frag read is ds_read_b128 at base+lane*16 (linear, no conflict,
// no swizzle needed). Round-8 counters showed per-wave 64KB W re-reads from
// L2 (Wh > L1) were the wall: MfmaUtil 3%, occ 24%.
// LDS (64KB) is reused after the K-loop for the Y-coalescing stage.
__global__ __launch_bounds__(512, 4) void gemm_kernel(
    const float* __restrict__ x,
    const unsigned short* __restrict__ Wh,   // [256][128] bf16
    unsigned short* __restrict__ Yh,         // [NNODES][128] bf16
    float* __restrict__ Z)                   // = d_out
{
    __shared__ unsigned short lds_buf[32768];   // 64KB: W frags, then Y stage
    const int tid  = threadIdx.x;
    const int wave = tid >> 6;
    const int lane = tid & 63;
    const int lrow = lane & 15;
    const int kgrp = lane >> 4;
    const int row0 = blockIdx.x * 128 + wave * 16;

    // ---- stage W into LDS, fragment-major (8 iters x 512 thr x 16B) ----
#pragma unroll
    for (int it = 0; it < 8; ++it) {
        const int i  = it * 512 + tid;          // chunk index 0..4095
        const int il = i & 63;
        const int ks = (i >> 6) & 3;
        const int ct = i >> 8;
        const int g  = (ct * 16 + (il & 15)) * 16 + ks * 4 + (il >> 4);
        *(ushort8*)(lds_buf + (size_t)i * 8) = *(const ushort8*)(Wh + (size_t)g * 8);
    }
    __syncthreads();

    // ---- K-loop: MFMA with B-frags from LDS ----
    int arow = row0 + lrow;
    if (arow >= NNODES) arow = NNODES - 1;      // clamped rows never stored
    const float* xrow = x + (size_t)arow * DIM + kgrp * 8;

    f32x4 acc[16];
#pragma unroll
    for (int i = 0; i < 16; ++i) acc[i] = (f32x4){0.f, 0.f, 0.f, 0.f};

#pragma unroll
    for (int ks = 0; ks < 4; ++ks) {
        float4 a0 = *(const float4*)(xrow + ks * 32);
        float4 a1 = *(const float4*)(xrow + ks * 32 + 4);
        short8 af;
        af[0] = (short)f2bf(a0.x); af[1] = (short)f2bf(a0.y);
        af[2] = (short)f2bf(a0.z); af[3] = (short)f2bf(a0.w);
        af[4] = (short)f2bf(a1.x); af[5] = (short)f2bf(a1.y);
        af[6] = (short)f2bf(a1.z); af[7] = (short)f2bf(a1.w);
#pragma unroll
        for (int ct = 0; ct < 16; ++ct) {
            short8 bf = *(const short8*)(lds_buf + (size_t)((ct * 4 + ks) * 64 + lane) * 8);
            acc[ct] = __builtin_amdgcn_mfma_f32_16x16x32_bf16(af, bf, acc[ct], 0, 0, 0);
        }
    }

    // ---- Z half: direct fp32 stores (64B-dense per 16-lane group) ----
#pragma unroll
    for (int ct = 8; ct < 16; ++ct) {
        const int col = (ct - 8) * 16 + lrow;
#pragma unroll
        for (int r = 0; r < 4; ++r) {
            const int row = row0 + kgrp * 4 + r;
            if (row < NNODES)
                Z[(size_t)row * DIM + col] = acc[ct][r];
        }
    }

    __syncthreads();   // all W reads done -> safe to reuse LDS for Y

    // ---- Y half -> LDS stage (cross-lane exchange) ----
    unsigned short* wl = lds_buf + (size_t)wave * 16 * YSTRIDE;
#pragma unroll
    for (int ct = 0; ct < 8; ++ct) {
        const int scol = ct * 16 + lrow;
#pragma unroll
        for (int r = 0; r < 4; ++r)
            wl[(kgrp * 4 + r) * YSTRIDE + scol] = f2bf(acc[ct][r]);
    }

    __syncthreads();   // orders LDS writes before cross-lane readback (r7 lesson)

    // ---- Y readback + coalesced dwordx4 stores ----
#pragma unroll
    for (int i = 0; i < 4; ++i) {
        const int row = 4 * i + kgrp;
        if (row0 + row < NNODES) {
            ushort8 v = *(const ushort8*)(wl + row * YSTRIDE + lrow * 8);
            *(ushort8*)(Yh + (size_t)(row0 + row) * DIM + lrow * 8) = v;
        }
    }
}

// --- aggregate: out[n] = relu(invd * sum_{j in N(n)} Y[j] + Z[n] + b) ---
// one wave per node; lane owns 2 cols. deg<=8 resolves in ONE parallel
// latency round (clamped in-bounds loads + wave-uniform guards).
__global__ __launch_bounds__(256) void aggregate_kernel(
    const unsigned short* __restrict__ Yh,
    const int* __restrict__ off,
    const int* __restrict__ adj,
    const float* __restrict__ bias,
    float* __restrict__ out)                 // in: Z, out: result (in-place)
{
    const int wave = threadIdx.x >> 6;
    const int lane = threadIdx.x & 63;
    const int n = blockIdx.x * 4 + wave;
    if (n >= NNODES) return;

    const int o0 = off[n], o1 = off[n + 1];
    float ax = 0.f, ay = 0.f;

    if (o0 < o1) {
        int j = o0;
        for (; j + 8 <= o1; j += 8) {        // full batches (deg >= 8)
            int s[8];
#pragma unroll
            for (int k = 0; k < 8; ++k) s[k] = adj[j + k];
            unsigned v[8];
#pragma unroll
            for (int k = 0; k < 8; ++k)
                v[k] = *(const unsigned*)(Yh + (size_t)s[k] * DIM + lane * 2);
#pragma unroll
            for (int k = 0; k < 8; ++k) {
                ax += __uint_as_float(v[k] << 16);
                ay += __uint_as_float(v[k] & 0xFFFF0000u);
            }
        }
        const int rem = o1 - j;              // 0..7, wave-uniform
        if (rem) {
            int s[8];
#pragma unroll
            for (int k = 0; k < 8; ++k) {
                int jj = j + k;
                s[k] = adj[(jj < o1) ? jj : (o1 - 1)];   // clamped: in-bounds
            }
            unsigned v[8];
#pragma unroll
            for (int k = 0; k < 8; ++k)
                v[k] = *(const unsigned*)(Yh + (size_t)s[k] * DIM + lane * 2);
#pragma unroll
            for (int k = 0; k < 8; ++k) {
                if (k < rem) {               // wave-uniform guard
                    ax += __uint_as_float(v[k] << 16);
                    ay += __uint_as_float(v[k] & 0xFFFF0000u);
                }
            }
        }
    }

    const float invd = 1.0f / fmaxf((float)(o1 - o0), 1.0f);
    float2 z  = *(const float2*)(out  + (size_t)n * DIM + lane * 2);
    float2 bb = *(const float2*)(bias + lane * 2);
    float2 o;
    o.x = fmaxf(ax * invd + z.x + bb.x, 0.f);
    o.y = fmaxf(ay * invd + z.y + bb.y, 0.f);
    *(float2*)(out + (size_t)n * DIM + lane * 2) = o;
}

extern "C" void kernel_launch(void* const* d_in, const int* in_sizes, int n_in,
                              void* d_out, int out_size, void* d_ws, size_t ws_size,
                              hipStream_t stream) {
    const float* x  = (const float*)d_in[0];
    const int*   ei = (const int*)d_in[1];   // int32 (harness converts int64)
    const float* Wl = (const float*)d_in[2];
    const float* Wr = (const float*)d_in[3];
    const float* b  = (const float*)d_in[4];
    float* out = (float*)d_out;

    // ws layout (~29.6 MB):
    //   [0,     512K) off   int[NNODES+1]
    //   [512K,    1M) deg   int[NNODES] (doubles as fill cursor)
    //   [1M,    3.5M) adj   int[NEDGES]
    //   [3.5M,  +4K ) bsum ; [3.5M+4K, +4K) boff
    //   [3.75M, +64K) Wh    bf16[256*128]
    //   [4M,  +25.6M) Yh    bf16[NNODES*128]
    int*            off  = (int*)d_ws;
    int*            deg  = (int*)((char*)d_ws + (512 << 10));
    int*            adj  = (int*)((char*)d_ws + (1 << 20));
    int*            bsum = (int*)((char*)d_ws + 3584 * 1024);
    int*            boff = (int*)((char*)d_ws + 3588 * 1024);
    unsigned short* Wh   = (unsigned short*)((char*)d_ws + 3840 * 1024);
    unsigned short* Yh   = (unsigned short*)((char*)d_ws + (4 << 20));

    hipMemsetAsync(deg, 0, NNODES * sizeof(int), stream);

    convert_w_kernel<<<(2 * DIM * DIM + 255) / 256, 256, 0, stream>>>(Wl, Wr, Wh);
    degree_kernel<<<(NEDGES + 255) / 256, 256, 0, stream>>>(ei, deg);
    block_sum_kernel<<<NSCAN, SCAN_B, 0, stream>>>(deg, bsum);
    scan_small_kernel<<<1, 128, 0, stream>>>(bsum, boff);
    scan_block_kernel<<<NSCAN, SCAN_B, 0, stream>>>(deg, boff, off);
    fill_kernel<<<(NEDGES + 255) / 256, 256, 0, stream>>>(ei, off, deg, adj);

    gemm_kernel<<<(NNODES + 127) / 128, 512, 0, stream>>>(x, Wh, Yh, out);
    aggregate_kernel<<<(NNODES + 3) / 4, 256, 0, stream>>>(Yh, off, adj, b, out);
}